// Round 2
// baseline (704.246 us; speedup 1.0000x reference)
//
#include <hip/hip_runtime.h>

#define BB 2
#define CC 64
#define HH 128
#define WW 128
#define OC 64

struct Meta { int i0, i1, i2, i3; float w0, w1, w2, w3; int dst; };

__global__ __launch_bounds__(256, 4) void dcn_fused2(
    const float* __restrict__ x,
    const float* __restrict__ Wp,
    const float* __restrict__ bp,
    const float* __restrict__ Wc,
    float* __restrict__ out)
{
    // unioned LDS: [0,4608) = offset-conv partials (phase 0 only)
    //              [0,6912) = double-buffered sX (2x1152) + sW (2x2304)
    __shared__ __align__(16) float smem[6912];   // 27648 B

    const int t  = threadIdx.x;
    const int bx = blockIdx.x;
    const int b  = bx >> 9;             // 512 blocks per batch
    const int i  = (bx >> 2) & 127;
    const int j0 = (bx & 3) << 5;       // 4 x 32-wide column strips

    // ---------------- phase 0a: offset-conv partials ----------------
    {
        const int grp = t >> 5;         // 8 channel groups of 8
        const int pp  = t & 31;
        const int j   = j0 + pp;
        float part[18];
#pragma unroll
        for (int o = 0; o < 18; ++o) part[o] = 0.f;
        const float* xg = x + (b * CC + grp * 8) * (HH * WW);
        for (int c = 0; c < 8; ++c) {
            float xv[9];
#pragma unroll
            for (int dx = 0; dx < 3; ++dx) {
                const int ii = i + dx - 1;
                const bool okx = (unsigned)ii < (unsigned)HH;
#pragma unroll
                for (int dy = 0; dy < 3; ++dy) {
                    const int jj = j + dy - 1;
                    const bool ok = okx && ((unsigned)jj < (unsigned)WW);
                    xv[dx * 3 + dy] = ok ? xg[c * (HH * WW) + ii * WW + jj] : 0.f;
                }
            }
            const float* wp = Wp + (grp * 8 + c) * 9;
#pragma unroll
            for (int o = 0; o < 18; ++o) {
                const float* w = wp + o * 576;
#pragma unroll
                for (int k = 0; k < 9; ++k)
                    part[o] = fmaf(xv[k], w[k], part[o]);
            }
        }
#pragma unroll
        for (int o = 0; o < 18; ++o)
            smem[grp * 576 + pp * 18 + o] = part[o];   // [grp][pos][o], stride-18 = 2-way (free)
    }
    __syncthreads();

    // ---------------- phase 0b: sampling metadata ----------------
    auto mkmeta = [&](int pos, int n) -> Meta {
        const int kx = n / 3, ky = n - kx * 3;
        float offx = bp[n], offy = bp[9 + n];
#pragma unroll
        for (int g = 0; g < 8; ++g) {
            offx += smem[g * 576 + pos * 18 + n];
            offy += smem[g * 576 + pos * 18 + 9 + n];
        }
        const float px = offx + (float)(kx - 1) + (float)(i + 1);
        const float py = offy + (float)(ky - 1) + (float)(j0 + pos + 1);
        const float flx = floorf(px), fly = floorf(py);
        const float qltx = fminf(fmaxf(flx,       0.f), 129.f);
        const float qlty = fminf(fmaxf(fly,       0.f), 129.f);
        const float qrbx = fminf(fmaxf(flx + 1.f, 0.f), 129.f);
        const float qrby = fminf(fmaxf(fly + 1.f, 0.f), 129.f);
        const float pxc  = fminf(fmaxf(px, 0.f), 129.f);
        const float pyc  = fminf(fmaxf(py, 0.f), 129.f);
        const float gx0 = 1.f + (qltx - pxc), gx1 = 1.f - (qrbx - pxc);
        const float gy0 = 1.f + (qlty - pyc), gy1 = 1.f - (qrby - pyc);
        const int rx0 = (int)qltx - 1, rx1 = (int)qrbx - 1;
        const int ry0 = (int)qlty - 1, ry1 = (int)qrby - 1;
        const bool vx0 = (unsigned)rx0 < (unsigned)HH, vx1 = (unsigned)rx1 < (unsigned)HH;
        const bool vy0 = (unsigned)ry0 < (unsigned)WW, vy1 = (unsigned)ry1 < (unsigned)WW;
        Meta M;
        M.i0 = (vx0 && vy0) ? rx0 * WW + ry0 : 0;  M.w0 = (vx0 && vy0) ? gx0 * gy0 : 0.f;
        M.i1 = (vx1 && vy1) ? rx1 * WW + ry1 : 0;  M.w1 = (vx1 && vy1) ? gx1 * gy1 : 0.f;
        M.i2 = (vx0 && vy1) ? rx0 * WW + ry1 : 0;  M.w2 = (vx0 && vy1) ? gx0 * gy1 : 0.f;
        M.i3 = (vx1 && vy0) ? rx1 * WW + ry0 : 0;  M.w3 = (vx1 && vy0) ? gx1 * gy0 : 0.f;
        M.dst = n * 32 + pos;
        return M;
    };

    Meta M0 = mkmeta(t & 31, t >> 5);          // n = 0..7
    Meta M1;
    M1.i0 = M1.i1 = M1.i2 = M1.i3 = 0; M1.w0 = M1.w1 = M1.w2 = M1.w3 = 0.f; M1.dst = 0;
    if (t < 32) M1 = mkmeta(t, 8);             // n = 8 row
    __syncthreads();   // s_part reads done; smem becomes GEMM buffers

    // ---------------- pipelined main loop ----------------
    float acc[4][2];
#pragma unroll
    for (int m = 0; m < 4; ++m) { acc[m][0] = 0.f; acc[m][1] = 0.f; }

    const int oc4  = (t >> 4) << 2;    // GEMM: 4 oc
    const int pos2 = (t & 15) << 1;    // GEMM: 2 pos
    const int woc  = t >> 2;           // W-stage: oc 0..63
    const int wcc  = t & 3;            // W-stage: chunk-channel 0..3
    const float* xb = x + b * (CC * HH * WW);

    float g0[4][4], g1[4][4], gw[9];

    auto GATHER = [&](int k) {
        const float* xcb = xb + (k * 4) * (HH * WW);
#pragma unroll
        for (int cc = 0; cc < 4; ++cc) {
            const float* xc = xcb + cc * (HH * WW);
            g0[cc][0] = xc[M0.i0];
            g0[cc][1] = xc[M0.i1];
            g0[cc][2] = xc[M0.i2];
            g0[cc][3] = xc[M0.i3];
        }
        if (t < 32) {
#pragma unroll
            for (int cc = 0; cc < 4; ++cc) {
                const float* xc = xcb + cc * (HH * WW);
                g1[cc][0] = xc[M1.i0];
                g1[cc][1] = xc[M1.i1];
                g1[cc][2] = xc[M1.i2];
                g1[cc][3] = xc[M1.i3];
            }
        }
        const float* wsrc = Wc + woc * 576 + (k * 4 + wcc) * 9;
#pragma unroll
        for (int n = 0; n < 9; ++n) gw[n] = wsrc[n];
    };

    auto WSTORE = [&](float* bX, float* bW) {
#pragma unroll
        for (int cc = 0; cc < 4; ++cc) {
            float v = g0[cc][0] * M0.w0;
            v = fmaf(g0[cc][1], M0.w1, v);
            v = fmaf(g0[cc][2], M0.w2, v);
            v = fmaf(g0[cc][3], M0.w3, v);
            bX[cc * 288 + M0.dst] = v;
        }
        if (t < 32) {
#pragma unroll
            for (int cc = 0; cc < 4; ++cc) {
                float v = g1[cc][0] * M1.w0;
                v = fmaf(g1[cc][1], M1.w1, v);
                v = fmaf(g1[cc][2], M1.w2, v);
                v = fmaf(g1[cc][3], M1.w3, v);
                bX[cc * 288 + M1.dst] = v;
            }
        }
#pragma unroll
        for (int n = 0; n < 9; ++n)
            bW[wcc * 576 + n * 64 + woc] = gw[n];
    };

    auto GEMM = [&](const float* bX, const float* bW) {
#pragma unroll
        for (int cc = 0; cc < 4; ++cc)
#pragma unroll
            for (int n = 0; n < 9; ++n) {
                const float4 wr = *(const float4*)&bW[cc * 576 + n * 64 + oc4];
                const float2 xr = *(const float2*)&bX[cc * 288 + n * 32 + pos2];
                acc[0][0] = fmaf(wr.x, xr.x, acc[0][0]);
                acc[0][1] = fmaf(wr.x, xr.y, acc[0][1]);
                acc[1][0] = fmaf(wr.y, xr.x, acc[1][0]);
                acc[1][1] = fmaf(wr.y, xr.y, acc[1][1]);
                acc[2][0] = fmaf(wr.z, xr.x, acc[2][0]);
                acc[2][1] = fmaf(wr.z, xr.y, acc[2][1]);
                acc[3][0] = fmaf(wr.w, xr.x, acc[3][0]);
                acc[3][1] = fmaf(wr.w, xr.y, acc[3][1]);
            }
    };

    float* const sX0 = smem;
    float* const sX1 = smem + 1152;
    float* const sW0 = smem + 2304;
    float* const sW1 = smem + 4608;

    GATHER(0);
    WSTORE(sX0, sW0);
    __syncthreads();
    for (int k = 1; k < 16; ++k) {
        GATHER(k);                                     // loads for chunk k in flight...
        const float* gX = (k & 1) ? sX0 : sX1;
        const float* gW = (k & 1) ? sW0 : sW1;
        GEMM(gX, gW);                                  // ...hidden under chunk k-1 GEMM
        float* bX = (k & 1) ? sX1 : sX0;
        float* bW = (k & 1) ? sW1 : sW0;
        WSTORE(bX, bW);
        __syncthreads();
    }
    GEMM(sX1, sW1);                                    // chunk 15

    // ---------------- epilogue ----------------
#pragma unroll
    for (int m = 0; m < 4; ++m) {
        float2 v = make_float2(acc[m][0], acc[m][1]);
        *reinterpret_cast<float2*>(&out[((b * OC + oc4 + m) * HH + i) * WW + j0 + pos2]) = v;
    }
}

extern "C" void kernel_launch(void* const* d_in, const int* in_sizes, int n_in,
                              void* d_out, int out_size, void* d_ws, size_t ws_size,
                              hipStream_t stream) {
    const float* x  = (const float*)d_in[0];
    const float* Wp = (const float*)d_in[1];
    const float* bp = (const float*)d_in[2];
    const float* Wc = (const float*)d_in[3];
    float* out = (float*)d_out;
    dcn_fused2<<<dim3(BB * HH * 4), dim3(256), 0, stream>>>(x, Wp, bp, Wc, out);
}

// Round 3
// 159.262 us; speedup vs baseline: 4.4219x; 4.4219x over previous
//
#include <hip/hip_runtime.h>

#define BB 2
#define CC 64
#define HH 128
#define WW 128
#define OC 64
#define HW (HH * WW)

struct Meta { int i0, i1, i2, i3; float w0, w1, w2, w3; int dst; };

__global__ __launch_bounds__(256) void dcn_fused3(
    const float* __restrict__ x,
    const float* __restrict__ Wp,
    const float* __restrict__ bp,
    const float* __restrict__ Wc,
    float* __restrict__ out)
{
    // phase 0: partials [8 grp][32 pos][18]  = 4608 floats
    // main:    sX dbuf 2*576 = [0,1152) ; sW dbuf 2*1152 = [1152,3456)
    __shared__ __align__(16) float smem[4608];

    const int t  = threadIdx.x;
    const int bx = blockIdx.x;
    const int b  = bx >> 9;             // 512 blocks per batch
    const int i  = (bx >> 2) & 127;
    const int j0 = (bx & 3) << 5;       // 4 x 32-wide column strips

    // ---------------- phase 0a: offset-conv partials ----------------
    {
        const int grp = t >> 5;         // 8 channel groups of 8
        const int pp  = t & 31;
        const int j   = j0 + pp;
        float part[18];
#pragma unroll
        for (int o = 0; o < 18; ++o) part[o] = 0.f;
        const float* xg = x + (b * CC + grp * 8) * HW;
        for (int c = 0; c < 8; ++c) {
            float xv[9];
#pragma unroll
            for (int dx = 0; dx < 3; ++dx) {
                const int ii = i + dx - 1;
                const bool okx = (unsigned)ii < (unsigned)HH;
#pragma unroll
                for (int dy = 0; dy < 3; ++dy) {
                    const int jj = j + dy - 1;
                    const bool ok = okx && ((unsigned)jj < (unsigned)WW);
                    xv[dx * 3 + dy] = ok ? xg[c * HW + ii * WW + jj] : 0.f;
                }
            }
            const float* wp = Wp + (grp * 8 + c) * 9;
#pragma unroll
            for (int o = 0; o < 18; ++o) {
                const float* w = wp + o * 576;
#pragma unroll
                for (int k = 0; k < 9; ++k)
                    part[o] = fmaf(xv[k], w[k], part[o]);
            }
        }
#pragma unroll
        for (int o = 0; o < 18; ++o)
            smem[grp * 576 + pp * 18 + o] = part[o];
    }
    __syncthreads();

    // ---------------- phase 0b: sampling metadata ----------------
    auto mkmeta = [&](int pos, int n) -> Meta {
        const int kx = n / 3, ky = n - kx * 3;
        float offx = bp[n], offy = bp[9 + n];
#pragma unroll
        for (int g = 0; g < 8; ++g) {
            offx += smem[g * 576 + pos * 18 + n];
            offy += smem[g * 576 + pos * 18 + 9 + n];
        }
        const float px = offx + (float)(kx - 1) + (float)(i + 1);
        const float py = offy + (float)(ky - 1) + (float)(j0 + pos + 1);
        const float flx = floorf(px), fly = floorf(py);
        const float qltx = fminf(fmaxf(flx,       0.f), 129.f);
        const float qlty = fminf(fmaxf(fly,       0.f), 129.f);
        const float qrbx = fminf(fmaxf(flx + 1.f, 0.f), 129.f);
        const float qrby = fminf(fmaxf(fly + 1.f, 0.f), 129.f);
        const float pxc  = fminf(fmaxf(px, 0.f), 129.f);
        const float pyc  = fminf(fmaxf(py, 0.f), 129.f);
        const float gx0 = 1.f + (qltx - pxc), gx1 = 1.f - (qrbx - pxc);
        const float gy0 = 1.f + (qlty - pyc), gy1 = 1.f - (qrby - pyc);
        const int rx0 = (int)qltx - 1, rx1 = (int)qrbx - 1;
        const int ry0 = (int)qlty - 1, ry1 = (int)qrby - 1;
        const bool vx0 = (unsigned)rx0 < (unsigned)HH, vx1 = (unsigned)rx1 < (unsigned)HH;
        const bool vy0 = (unsigned)ry0 < (unsigned)WW, vy1 = (unsigned)ry1 < (unsigned)WW;
        Meta M;
        M.i0 = (vx0 && vy0) ? rx0 * WW + ry0 : 0;  M.w0 = (vx0 && vy0) ? gx0 * gy0 : 0.f;
        M.i1 = (vx1 && vy1) ? rx1 * WW + ry1 : 0;  M.w1 = (vx1 && vy1) ? gx1 * gy1 : 0.f;
        M.i2 = (vx0 && vy1) ? rx0 * WW + ry1 : 0;  M.w2 = (vx0 && vy1) ? gx0 * gy1 : 0.f;
        M.i3 = (vx1 && vy0) ? rx1 * WW + ry0 : 0;  M.w3 = (vx1 && vy0) ? gx1 * gy0 : 0.f;
        M.dst = n * 32 + pos;
        return M;
    };

    Meta M0 = mkmeta(t & 31, t >> 5);          // n = 0..7
    Meta M1;
    M1.i0 = M1.i1 = M1.i2 = M1.i3 = 0; M1.w0 = M1.w1 = M1.w2 = M1.w3 = 0.f; M1.dst = 0;
    if (t < 32) M1 = mkmeta(t, 8);             // n = 8 row
    __syncthreads();   // partials consumed; smem becomes GEMM buffers

    // ---------------- main loop: 32 rounds of 2 channels ----------------
    float acc[4][2];
#pragma unroll
    for (int m = 0; m < 4; ++m) { acc[m][0] = 0.f; acc[m][1] = 0.f; }

    const int oc4  = (t >> 4) << 2;    // GEMM: 4 oc
    const int pos2 = (t & 15) << 1;    // GEMM: 2 pos
    const int woc  = t & 63;           // W-stage: oc lane
    const int g    = __builtin_amdgcn_readfirstlane(t >> 6);  // wave-uniform group
    const int r0   = (g < 2) ? g * 5 : 10 + (g - 2) * 4;      // 5,5,4,4 split of 18
    const int rc   = (g < 2) ? 5 : 4;
    const float* xb = x + b * (CC * HW);

    auto stage = [&](int k, int d) {
        const float* xc0 = xb + (2 * k) * HW;
        float* bX = smem + d * 576;
        float* bW = smem + 1152 + d * 1152;
#pragma unroll
        for (int ch = 0; ch < 2; ++ch) {
            const float* xc = xc0 + ch * HW;
            float v = xc[M0.i0] * M0.w0;
            v = fmaf(xc[M0.i1], M0.w1, v);
            v = fmaf(xc[M0.i2], M0.w2, v);
            v = fmaf(xc[M0.i3], M0.w3, v);
            bX[ch * 288 + M0.dst] = v;
        }
        if (t < 32) {
#pragma unroll
            for (int ch = 0; ch < 2; ++ch) {
                const float* xc = xc0 + ch * HW;
                float v = xc[M1.i0] * M1.w0;
                v = fmaf(xc[M1.i1], M1.w1, v);
                v = fmaf(xc[M1.i2], M1.w2, v);
                v = fmaf(xc[M1.i3], M1.w3, v);
                bX[ch * 288 + M1.dst] = v;
            }
        }
#pragma unroll
        for (int q = 0; q < 5; ++q) {
            if (q < rc) {
                const int r  = r0 + q;
                const int ch = (r >= 9) ? 1 : 0;
                const int n  = r - ch * 9;
                bW[ch * 576 + n * 64 + woc] = Wc[woc * 576 + (2 * k + ch) * 9 + n];
            }
        }
    };

    auto gemm = [&](int d) {
        const float* bX = smem + d * 576;
        const float* bW = smem + 1152 + d * 1152;
#pragma unroll
        for (int ch = 0; ch < 2; ++ch)
#pragma unroll
            for (int n = 0; n < 9; ++n) {
                const float4 wr = *(const float4*)&bW[ch * 576 + n * 64 + oc4];
                const float2 xr = *(const float2*)&bX[ch * 288 + n * 32 + pos2];
                acc[0][0] = fmaf(wr.x, xr.x, acc[0][0]);
                acc[0][1] = fmaf(wr.x, xr.y, acc[0][1]);
                acc[1][0] = fmaf(wr.y, xr.x, acc[1][0]);
                acc[1][1] = fmaf(wr.y, xr.y, acc[1][1]);
                acc[2][0] = fmaf(wr.z, xr.x, acc[2][0]);
                acc[2][1] = fmaf(wr.z, xr.y, acc[2][1]);
                acc[3][0] = fmaf(wr.w, xr.x, acc[3][0]);
                acc[3][1] = fmaf(wr.w, xr.y, acc[3][1]);
            }
    };

    stage(0, 0);
    __syncthreads();
    for (int k = 0; k < 31; ++k) {
        stage(k + 1, (k + 1) & 1);   // writes other buffer while...
        gemm(k & 1);                 // ...GEMM reads current (waves overlap via TLP)
        __syncthreads();
    }
    gemm(1);                         // round 31

    // ---------------- epilogue ----------------
#pragma unroll
    for (int m = 0; m < 4; ++m) {
        float2 v = make_float2(acc[m][0], acc[m][1]);
        *reinterpret_cast<float2*>(&out[((b * OC + oc4 + m) * HH + i) * WW + j0 + pos2]) = v;
    }
}

extern "C" void kernel_launch(void* const* d_in, const int* in_sizes, int n_in,
                              void* d_out, int out_size, void* d_ws, size_t ws_size,
                              hipStream_t stream) {
    const float* x  = (const float*)d_in[0];
    const float* Wp = (const float*)d_in[1];
    const float* bp = (const float*)d_in[2];
    const float* Wc = (const float*)d_in[3];
    float* out = (float*)d_out;
    dcn_fused3<<<dim3(BB * HH * 4), dim3(256), 0, stream>>>(x, Wp, bp, Wc, out);
}